// Round 2
// baseline (60.314 us; speedup 1.0000x reference)
//
#include <hip/hip_runtime.h>
#include <hip/hip_bf16.h>

#define ALPHA 0.2f

constexpr int B = 8, N = 2048, F = 64;

typedef __attribute__((ext_vector_type(8))) short bf16x8;
typedef __attribute__((ext_vector_type(16))) float f32x16;

__device__ __forceinline__ float lrelu(float x) { return fmaxf(x, ALPHA * x); }

// ---------------- K1: h = inp@W ; f1 = h@a1 ; f2 = h@a2 ; hT (bf16, transposed,
//                   PRE-XOR-SWIZZLED within each 128-col tile for k3's glds path)
__global__ __launch_bounds__(256) void k1_project(
    const float* __restrict__ inp, const float* __restrict__ W,
    const float* __restrict__ a,
    __hip_bfloat16* __restrict__ hT, float* __restrict__ f1, float* __restrict__ f2)
{
  __shared__ float Wl[64][64];        // 16KB
  __shared__ float inpl[32][64];      // 8KB
  __shared__ float red[32][8][2];     // 2KB
  __shared__ __hip_bfloat16 hl[32][64]; // 4KB
  __shared__ float al[128];

  const int tid = threadIdx.x;
  const int g0 = blockIdx.x * 32;     // global row in [0, B*N)
  const int b = g0 / N, i0 = g0 % N;

  #pragma unroll
  for (int m = 0; m < 4; ++m) {
    int off = m * 1024 + tid * 4;
    *(float4*)((float*)Wl + off) = *(const float4*)(W + off);
  }
  #pragma unroll
  for (int m = 0; m < 2; ++m) {
    int off = m * 1024 + tid * 4;
    *(float4*)((float*)inpl + off) = *(const float4*)(inp + (size_t)g0 * F + off);
  }
  if (tid < 128) al[tid] = a[tid];
  __syncthreads();

  const int r = tid >> 3, c0 = (tid & 7) * 8;
  float acc[8];
  #pragma unroll
  for (int c = 0; c < 8; ++c) acc[c] = 0.f;
  for (int k = 0; k < 64; ++k) {
    float v = inpl[r][k];
    #pragma unroll
    for (int c = 0; c < 8; ++c) acc[c] += v * Wl[k][c0 + c];
  }
  float p1 = 0.f, p2 = 0.f;
  unsigned short hb[8] __attribute__((aligned(16)));
  #pragma unroll
  for (int c = 0; c < 8; ++c) {
    p1 += acc[c] * al[c0 + c];
    p2 += acc[c] * al[64 + c0 + c];
    __hip_bfloat16 hv = __float2bfloat16(acc[c]);
    hb[c] = *(unsigned short*)&hv;
  }
  red[r][tid & 7][0] = p1;
  red[r][tid & 7][1] = p2;
  *(uint4*)&hl[r][c0] = *(uint4*)hb;
  __syncthreads();

  if (tid < 32) {
    float s1 = 0.f, s2 = 0.f;
    #pragma unroll
    for (int m = 0; m < 8; ++m) { s1 += red[tid][m][0]; s2 += red[tid][m][1]; }
    f1[g0 + tid] = s1;
    f2[g0 + tid] = s2;
  }
  // transposed store, pre-swizzled: column j of feature-row c lands at
  // (j & ~127) | ((j & 127) ^ ((c & 7) << 3)). Our 8-j group is 8-aligned and
  // the XOR only touches bits 3..5, so it maps aligned-8 -> aligned-8.
  const int c = tid >> 2, r8 = (tid & 3) * 8;
  unsigned short tb[8] __attribute__((aligned(16)));
  #pragma unroll
  for (int m = 0; m < 8; ++m) tb[m] = *(unsigned short*)&hl[r8 + m][c];
  const int jb = i0 + r8;
  const int jsw = (jb & ~127) | ((jb & 127) ^ ((c & 7) << 3));
  *(uint4*)(hT + ((size_t)b * F + c) * N + jsw) = *(uint4*)tb;
}

// ---------------- K2: per-batch unmasked max of f2 (upper bound for row max)
__global__ __launch_bounds__(256) void k2_f2max(const float* __restrict__ f2,
                                                float* __restrict__ f2max)
{
  __shared__ float s[256];
  const int b = blockIdx.x, tid = threadIdx.x;
  float m = -1e30f;
  for (int j = tid; j < N; j += 256) m = fmaxf(m, f2[b * N + j]);
  s[tid] = m;
  __syncthreads();
  for (int w = 128; w > 0; w >>= 1) {
    if (tid < w) s[tid] = fmaxf(s[tid], s[tid + w]);
    __syncthreads();
  }
  if (tid == 0) f2max[b] = s[0];
}

// ---------------- K3: fused mask + softmax + PV (bf16 MFMA) + elu
// Pipelined: reg-dbuf adj/f2, glds-dbuf hT, ONE barrier per j-tile.
__global__ __launch_bounds__(256) void k3_attn(
    const int* __restrict__ adj, const __hip_bfloat16* __restrict__ hT,
    const float* __restrict__ f1, const float* __restrict__ f2,
    const float* __restrict__ f2max, float* __restrict__ out)
{
  constexpr int RT = 32, JT = 128, NT = N / JT;  // 16 tiles
  __shared__ __hip_bfloat16 Pl[2][RT][JT];   // 16KB (XOR-swizzled in LDS)
  __shared__ __hip_bfloat16 Hl[2][F][JT];    // 32KB (linear; global is pre-swizzled)
  __shared__ float rs[RT][8];                // 1KB
  __shared__ float rcp_s[RT];
  __shared__ float redt[2][32][32];          // 8KB

  const int tid = threadIdx.x;
  const int lane = tid & 63, wid = tid >> 6;
  const int ct = wid >> 1, kh = wid & 1;     // col-tile, k-half
  const int bi = blockIdx.x;
  const int b = bi / (N / RT);
  const int i0 = (bi % (N / RT)) * RT;

  // score-phase mapping: 8 threads per row, 16 j's each
  const int r = tid >> 3, jc = (tid & 7) * 16;
  const float f1r = f1[b * N + i0 + r];
  const float Mr = lrelu(f1r + f2max[b]);    // >= true masked row max (lrelu monotone)

  const int* adjrow = adj + ((size_t)(b * N + i0 + r)) * N + jc;
  const float* f2row = f2 + b * N + jc;
  const int swp = (r & 7) << 3;

  // glds source mapping: wave wid stages rows [wid*16, wid*16+16) of the 64x128
  // tile; each of 4 issues covers 4 rows (64 lanes x 16B = 1KB).
  const __hip_bfloat16* hsrc =
      hT + ((size_t)b * F + (wid * 16 + (lane >> 4))) * N + (lane & 15) * 8;

  float rowsum = 0.f;
  f32x16 acc;
  #pragma unroll
  for (int q = 0; q < 16; ++q) acc[q] = 0.f;

  #define STAGE_H(T, BUFI)                                                      \
    do {                                                                        \
      const __hip_bfloat16* s0_ = hsrc + (T) * JT;                              \
      char* lb_ = (char*)(&Hl[(BUFI)][0][0]) + wid * 4096;                      \
      _Pragma("unroll")                                                         \
      for (int q_ = 0; q_ < 4; ++q_) {                                          \
        __builtin_amdgcn_global_load_lds(                                       \
            (const __attribute__((address_space(1))) void*)(s0_ + q_ * 4 * N),  \
            (__attribute__((address_space(3))) void*)(lb_ + q_ * 1024),         \
            16, 0, 0);                                                          \
      }                                                                         \
    } while (0)

  // prologue: tile 0 into regs + Hl[0]
  int4 av[4]; float4 fv[4];
  #pragma unroll
  for (int m = 0; m < 4; ++m) {
    av[m] = *(const int4*)(adjrow + m * 4);
    fv[m] = *(const float4*)(f2row + m * 4);
  }
  STAGE_H(0, 0);

  for (int t = 0; t < NT; ++t) {
    const int buf = t & 1;
    const bool more = (t + 1 < NT);
    int4 avn[4]; float4 fvn[4];
    if (more) {  // prefetch tile t+1 into regs; HBM latency hides under scores
      #pragma unroll
      for (int m = 0; m < 4; ++m) {
        avn[m] = *(const int4*)(adjrow + (t + 1) * JT + m * 4);
        fvn[m] = *(const float4*)(f2row + (t + 1) * JT + m * 4);
      }
    }

    // scores for tile t (from registers)
    unsigned short pb[16] __attribute__((aligned(16)));
    #pragma unroll
    for (int m = 0; m < 4; ++m) {
      const int* ai = (const int*)&av[m];
      const float* fe = (const float*)&fv[m];
      #pragma unroll
      for (int e = 0; e < 4; ++e) {
        float s = lrelu(f1r + fe[e]);
        float p = (ai[e] > 0) ? __expf(s - Mr) : 0.f;
        __hip_bfloat16 pbf = __float2bfloat16(p);
        rowsum += __bfloat162float(pbf);   // denominator from ROUNDED p
        pb[m * 4 + e] = *(unsigned short*)&pbf;
      }
    }
    *(uint4*)&Pl[buf][r][jc ^ swp]       = *(uint4*)&pb[0];
    *(uint4*)&Pl[buf][r][(jc + 8) ^ swp] = *(uint4*)&pb[8];

    __syncthreads();  // drains Pl writes + glds(t); MFMA(t-1) done in all waves

    if (more) STAGE_H(t + 1, buf ^ 1);  // safe: Hl[buf^1] last read pre-barrier

    const int arow = lane & 31;
    const int bcol = ct * 32 + (lane & 31);
    const int klo = kh * 64 + ((lane >> 5) * 8);
    #pragma unroll
    for (int s = 0; s < 4; ++s) {
      const int ak = klo + s * 16;
      bf16x8 af  = *(const bf16x8*)&Pl[buf][arow][ak ^ ((arow & 7) << 3)];
      bf16x8 bfr = *(const bf16x8*)&Hl[buf][bcol][ak ^ ((bcol & 7) << 3)];
      asm volatile("v_mfma_f32_32x32x16_bf16 %0, %1, %2, %0"
                   : "+v"(acc) : "v"(af), "v"(bfr));
    }

    if (more) {
      #pragma unroll
      for (int m = 0; m < 4; ++m) { av[m] = avn[m]; fv[m] = fvn[m]; }
    }
  }
  #undef STAGE_H

  rs[r][tid & 7] = rowsum;
  if (kh == 1) {
    #pragma unroll
    for (int q = 0; q < 16; ++q)
      redt[ct][(q & 3) + 8 * (q >> 2) + 4 * (lane >> 5)][lane & 31] = acc[q];
  }
  __syncthreads();
  if (tid < 32) {
    float s = 0.f;
    #pragma unroll
    for (int m = 0; m < 8; ++m) s += rs[tid][m];
    rcp_s[tid] = 1.0f / fmaxf(s, 1e-30f);
  }
  __syncthreads();
  if (kh == 0) {
    #pragma unroll
    for (int q = 0; q < 16; ++q) {
      const int row = (q & 3) + 8 * (q >> 2) + 4 * (lane >> 5);
      float v = (acc[q] + redt[ct][row][lane & 31]) * rcp_s[row];
      v = v > 0.f ? v : expm1f(v);
      out[((size_t)(b * N + i0 + row)) * F + ct * 32 + (lane & 31)] = v;
    }
  }
}

extern "C" void kernel_launch(void* const* d_in, const int* in_sizes, int n_in,
                              void* d_out, int out_size, void* d_ws, size_t ws_size,
                              hipStream_t stream) {
  const float* inp = (const float*)d_in[0];
  const int*   adj = (const int*)d_in[1];
  const float* W   = (const float*)d_in[2];
  const float* a   = (const float*)d_in[3];
  float* out = (float*)d_out;

  // workspace layout (~2.13 MB): hT bf16 (swizzled) | f1 | f2 | f2max
  char* ws = (char*)d_ws;
  __hip_bfloat16* hT = (__hip_bfloat16*)ws;
  float* f1  = (float*)(ws + (size_t)B * F * N * sizeof(__hip_bfloat16));
  float* f2  = f1 + (size_t)B * N;
  float* f2m = f2 + (size_t)B * N;

  hipLaunchKernelGGL(k1_project, dim3(B * N / 32), dim3(256), 0, stream, inp, W, a, hT, f1, f2);
  hipLaunchKernelGGL(k2_f2max, dim3(B), dim3(256), 0, stream, f2, f2m);
  hipLaunchKernelGGL(k3_attn, dim3(B * N / 32), dim3(256), 0, stream, adj, hT, f1, f2, f2m, out);
}

// Round 3
// 59.320 us; speedup vs baseline: 1.0168x; 1.0168x over previous
//
#include <hip/hip_runtime.h>
#include <hip/hip_bf16.h>

#define ALPHA 0.2f

constexpr int B = 8, N = 2048, F = 64;

typedef __attribute__((ext_vector_type(8))) short bf16x8;
typedef __attribute__((ext_vector_type(16))) float f32x16;

__device__ __forceinline__ float lrelu(float x) { return fmaxf(x, ALPHA * x); }

// ---------------- K1: h = inp@W ; f1 = h@a1 ; f2 = h@a2 ; hT (bf16, transposed,
//                   PRE-XOR-SWIZZLED within each 128-col tile for k3's glds path)
__global__ __launch_bounds__(256) void k1_project(
    const float* __restrict__ inp, const float* __restrict__ W,
    const float* __restrict__ a,
    __hip_bfloat16* __restrict__ hT, float* __restrict__ f1, float* __restrict__ f2)
{
  __shared__ float Wl[64][64];
  __shared__ float inpl[32][64];
  __shared__ float red[32][8][2];
  __shared__ __hip_bfloat16 hl[32][64];
  __shared__ float al[128];

  const int tid = threadIdx.x;
  const int g0 = blockIdx.x * 32;
  const int b = g0 / N, i0 = g0 % N;

  #pragma unroll
  for (int m = 0; m < 4; ++m) {
    int off = m * 1024 + tid * 4;
    *(float4*)((float*)Wl + off) = *(const float4*)(W + off);
  }
  #pragma unroll
  for (int m = 0; m < 2; ++m) {
    int off = m * 1024 + tid * 4;
    *(float4*)((float*)inpl + off) = *(const float4*)(inp + (size_t)g0 * F + off);
  }
  if (tid < 128) al[tid] = a[tid];
  __syncthreads();

  const int r = tid >> 3, c0 = (tid & 7) * 8;
  float acc[8];
  #pragma unroll
  for (int c = 0; c < 8; ++c) acc[c] = 0.f;
  for (int k = 0; k < 64; ++k) {
    float v = inpl[r][k];
    #pragma unroll
    for (int c = 0; c < 8; ++c) acc[c] += v * Wl[k][c0 + c];
  }
  float p1 = 0.f, p2 = 0.f;
  unsigned short hb[8] __attribute__((aligned(16)));
  #pragma unroll
  for (int c = 0; c < 8; ++c) {
    p1 += acc[c] * al[c0 + c];
    p2 += acc[c] * al[64 + c0 + c];
    __hip_bfloat16 hv = __float2bfloat16(acc[c]);
    hb[c] = *(unsigned short*)&hv;
  }
  red[r][tid & 7][0] = p1;
  red[r][tid & 7][1] = p2;
  *(uint4*)&hl[r][c0] = *(uint4*)hb;
  __syncthreads();

  if (tid < 32) {
    float s1 = 0.f, s2 = 0.f;
    #pragma unroll
    for (int m = 0; m < 8; ++m) { s1 += red[tid][m][0]; s2 += red[tid][m][1]; }
    f1[g0 + tid] = s1;
    f2[g0 + tid] = s2;
  }
  const int c = tid >> 2, r8 = (tid & 3) * 8;
  unsigned short tb[8] __attribute__((aligned(16)));
  #pragma unroll
  for (int m = 0; m < 8; ++m) tb[m] = *(unsigned short*)&hl[r8 + m][c];
  const int jb = i0 + r8;
  const int jsw = (jb & ~127) | ((jb & 127) ^ ((c & 7) << 3));
  *(uint4*)(hT + ((size_t)b * F + c) * N + jsw) = *(uint4*)tb;
}

// ---------------- K2: per-batch unmasked max of f2 (upper bound for row max)
__global__ __launch_bounds__(256) void k2_f2max(const float* __restrict__ f2,
                                                float* __restrict__ f2max)
{
  __shared__ float s[256];
  const int b = blockIdx.x, tid = threadIdx.x;
  float m = -1e30f;
  for (int j = tid; j < N; j += 256) m = fmaxf(m, f2[b * N + j]);
  s[tid] = m;
  __syncthreads();
  for (int w = 128; w > 0; w >>= 1) {
    if (tid < w) s[tid] = fmaxf(s[tid], s[tid + w]);
    __syncthreads();
  }
  if (tid == 0) f2max[b] = s[0];
}

// ---------------- K3: fused mask + softmax + PV (bf16 MFMA) + elu
// Lane-contiguous adj/f2 loads (128B/8-lane-group per instr); distance-2
// register prefetch; glds-dbuf hT; one barrier per j-tile.
__global__ __launch_bounds__(256) void k3_attn(
    const int* __restrict__ adj, const __hip_bfloat16* __restrict__ hT,
    const float* __restrict__ f1, const float* __restrict__ f2,
    const float* __restrict__ f2max, float* __restrict__ out)
{
  constexpr int RT = 32, JT = 128, NT = N / JT;  // 16 tiles
  __shared__ __hip_bfloat16 Pl[2][RT][JT];   // 16KB (XOR-swizzled)
  __shared__ __hip_bfloat16 Hl[2][F][JT];    // 32KB (linear; global pre-swizzled)
  __shared__ float rs[RT][8];                // 1KB
  __shared__ float rcp_s[RT];
  __shared__ float redt[2][32][32];          // 8KB

  const int tid = threadIdx.x;
  const int lane = tid & 63, wid = tid >> 6;
  const int ct = wid >> 1, kh = wid & 1;
  const int bi = blockIdx.x;
  const int b = bi / (N / RT);
  const int i0 = (bi % (N / RT)) * RT;

  // score mapping: 8 threads per row; thread q owns j in {4q+32m : m=0..3} per tile
  const int r = tid >> 3, q = tid & 7;
  const float f1r = f1[b * N + i0 + r];
  const float Mr = lrelu(f1r + f2max[b]);    // >= true masked row max (lrelu monotone)

  const int* adjrow = adj + ((size_t)(b * N + i0 + r)) * N + 4 * q;
  const float* f2base = f2 + b * N + 4 * q;
  const int swp = (r & 7) << 3;

  const __hip_bfloat16* hsrc =
      hT + ((size_t)b * F + (wid * 16 + (lane >> 4))) * N + (lane & 15) * 8;

  float rowsum = 0.f;
  f32x16 acc;
  #pragma unroll
  for (int z = 0; z < 16; ++z) acc[z] = 0.f;

  const int arow = lane & 31;
  const int bcol = ct * 32 + (lane & 31);
  const int klo = kh * 64 + ((lane >> 5) * 8);

  #define STAGE_H(T, BUFI)                                                      \
    do {                                                                        \
      const __hip_bfloat16* s0_ = hsrc + (T) * JT;                              \
      char* lb_ = (char*)(&Hl[(BUFI)][0][0]) + wid * 4096;                      \
      _Pragma("unroll")                                                         \
      for (int q_ = 0; q_ < 4; ++q_) {                                          \
        __builtin_amdgcn_global_load_lds(                                       \
            (const __attribute__((address_space(1))) void*)(s0_ + q_ * 4 * N),  \
            (__attribute__((address_space(3))) void*)(lb_ + q_ * 1024),         \
            16, 0, 0);                                                          \
      }                                                                         \
    } while (0)

  #define LOADSET(AV, FV, T)                                                    \
    do {                                                                        \
      _Pragma("unroll")                                                         \
      for (int m_ = 0; m_ < 4; ++m_) {                                          \
        AV[m_] = *(const int4*)(adjrow + (T) * JT + 32 * m_);                   \
        FV[m_] = *(const float4*)(f2base + (T) * JT + 32 * m_);                 \
      }                                                                         \
    } while (0)

  #define ITER(T, AV, FV, BUF)                                                  \
    do {                                                                        \
      _Pragma("unroll")                                                         \
      for (int m_ = 0; m_ < 4; ++m_) {                                          \
        const int* ai_ = (const int*)&AV[m_];                                   \
        const float* fe_ = (const float*)&FV[m_];                               \
        unsigned short pbm_[4] __attribute__((aligned(8)));                     \
        _Pragma("unroll")                                                       \
        for (int e_ = 0; e_ < 4; ++e_) {                                        \
          float s_ = lrelu(f1r + fe_[e_]);                                      \
          float p_ = (ai_[e_] > 0) ? __expf(s_ - Mr) : 0.f;                     \
          __hip_bfloat16 pbf_ = __float2bfloat16(p_);                           \
          rowsum += __bfloat162float(pbf_);                                     \
          pbm_[e_] = *(unsigned short*)&pbf_;                                   \
        }                                                                       \
        *(uint2*)&Pl[BUF][r][(4 * q + 32 * m_) ^ swp] = *(uint2*)pbm_;          \
      }                                                                         \
      __syncthreads();                                                          \
      if ((T) + 1 < NT) STAGE_H((T) + 1, (BUF) ^ 1);                            \
      if ((T) + 2 < NT) LOADSET(AV, FV, (T) + 2);                               \
      _Pragma("unroll")                                                         \
      for (int s_ = 0; s_ < 4; ++s_) {                                          \
        const int ak_ = klo + s_ * 16;                                          \
        bf16x8 af_ = *(const bf16x8*)&Pl[BUF][arow][ak_ ^ ((arow & 7) << 3)];   \
        bf16x8 bf_ = *(const bf16x8*)&Hl[BUF][bcol][ak_ ^ ((bcol & 7) << 3)];   \
        asm volatile("v_mfma_f32_32x32x16_bf16 %0, %1, %2, %0"                  \
                     : "+v"(acc) : "v"(af_), "v"(bf_));                         \
      }                                                                         \
    } while (0)

  // prologue: tiles 0,1 into register sets; tile 0 into Hl[0]
  int4 a0v[4], a1v[4]; float4 g0v[4], g1v[4];
  LOADSET(a0v, g0v, 0);
  LOADSET(a1v, g1v, 1);
  STAGE_H(0, 0);

  for (int t = 0; t < NT; t += 2) {
    ITER(t,     a0v, g0v, 0);
    ITER(t + 1, a1v, g1v, 1);
  }
  #undef ITER
  #undef LOADSET
  #undef STAGE_H

  rs[r][q] = rowsum;
  if (kh == 1) {
    #pragma unroll
    for (int z = 0; z < 16; ++z)
      redt[ct][(z & 3) + 8 * (z >> 2) + 4 * (lane >> 5)][lane & 31] = acc[z];
  }
  __syncthreads();
  if (tid < 32) {
    float s = 0.f;
    #pragma unroll
    for (int m = 0; m < 8; ++m) s += rs[tid][m];
    rcp_s[tid] = 1.0f / fmaxf(s, 1e-30f);
  }
  __syncthreads();
  if (kh == 0) {
    #pragma unroll
    for (int z = 0; z < 16; ++z) {
      const int row = (z & 3) + 8 * (z >> 2) + 4 * (lane >> 5);
      float v = (acc[z] + redt[ct][row][lane & 31]) * rcp_s[row];
      v = v > 0.f ? v : expm1f(v);
      out[((size_t)(b * N + i0 + row)) * F + ct * 32 + (lane & 31)] = v;
    }
  }
}

extern "C" void kernel_launch(void* const* d_in, const int* in_sizes, int n_in,
                              void* d_out, int out_size, void* d_ws, size_t ws_size,
                              hipStream_t stream) {
  const float* inp = (const float*)d_in[0];
  const int*   adj = (const int*)d_in[1];
  const float* W   = (const float*)d_in[2];
  const float* a   = (const float*)d_in[3];
  float* out = (float*)d_out;

  char* ws = (char*)d_ws;
  __hip_bfloat16* hT = (__hip_bfloat16*)ws;
  float* f1  = (float*)(ws + (size_t)B * F * N * sizeof(__hip_bfloat16));
  float* f2  = f1 + (size_t)B * N;
  float* f2m = f2 + (size_t)B * N;

  hipLaunchKernelGGL(k1_project, dim3(B * N / 32), dim3(256), 0, stream, inp, W, a, hT, f1, f2);
  hipLaunchKernelGGL(k2_f2max, dim3(B), dim3(256), 0, stream, f2, f2m);
  hipLaunchKernelGGL(k3_attn, dim3(B * N / 32), dim3(256), 0, stream, adj, hT, f1, f2, f2m, out);
}

// Round 4
// 58.848 us; speedup vs baseline: 1.0249x; 1.0080x over previous
//
#include <hip/hip_runtime.h>
#include <hip/hip_bf16.h>

#define ALPHA 0.2f

constexpr int B = 8, N = 2048, F = 64;

typedef __attribute__((ext_vector_type(8))) short bf16x8;
typedef __attribute__((ext_vector_type(16))) float f32x16;

__device__ __forceinline__ float lrelu(float x) { return fmaxf(x, ALPHA * x); }

// ---------------- K1: h = inp@W ; f1 = h@a1 ; f2 = h@a2 ; hT (bf16, transposed,
//                   PRE-XOR-SWIZZLED within each 128-col tile for k3's glds path)
__global__ __launch_bounds__(256) void k1_project(
    const float* __restrict__ inp, const float* __restrict__ W,
    const float* __restrict__ a,
    __hip_bfloat16* __restrict__ hT, float* __restrict__ f1, float* __restrict__ f2)
{
  __shared__ float Wl[64][64];
  __shared__ float inpl[32][64];
  __shared__ float red[32][8][2];
  __shared__ __hip_bfloat16 hl[32][64];
  __shared__ float al[128];

  const int tid = threadIdx.x;
  const int g0 = blockIdx.x * 32;
  const int b = g0 / N, i0 = g0 % N;

  #pragma unroll
  for (int m = 0; m < 4; ++m) {
    int off = m * 1024 + tid * 4;
    *(float4*)((float*)Wl + off) = *(const float4*)(W + off);
  }
  #pragma unroll
  for (int m = 0; m < 2; ++m) {
    int off = m * 1024 + tid * 4;
    *(float4*)((float*)inpl + off) = *(const float4*)(inp + (size_t)g0 * F + off);
  }
  if (tid < 128) al[tid] = a[tid];
  __syncthreads();

  const int r = tid >> 3, c0 = (tid & 7) * 8;
  float acc[8];
  #pragma unroll
  for (int c = 0; c < 8; ++c) acc[c] = 0.f;
  for (int k = 0; k < 64; ++k) {
    float v = inpl[r][k];
    #pragma unroll
    for (int c = 0; c < 8; ++c) acc[c] += v * Wl[k][c0 + c];
  }
  float p1 = 0.f, p2 = 0.f;
  unsigned short hb[8] __attribute__((aligned(16)));
  #pragma unroll
  for (int c = 0; c < 8; ++c) {
    p1 += acc[c] * al[c0 + c];
    p2 += acc[c] * al[64 + c0 + c];
    __hip_bfloat16 hv = __float2bfloat16(acc[c]);
    hb[c] = *(unsigned short*)&hv;
  }
  red[r][tid & 7][0] = p1;
  red[r][tid & 7][1] = p2;
  *(uint4*)&hl[r][c0] = *(uint4*)hb;
  __syncthreads();

  if (tid < 32) {
    float s1 = 0.f, s2 = 0.f;
    #pragma unroll
    for (int m = 0; m < 8; ++m) { s1 += red[tid][m][0]; s2 += red[tid][m][1]; }
    f1[g0 + tid] = s1;
    f2[g0 + tid] = s2;
  }
  const int c = tid >> 2, r8 = (tid & 3) * 8;
  unsigned short tb[8] __attribute__((aligned(16)));
  #pragma unroll
  for (int m = 0; m < 8; ++m) tb[m] = *(unsigned short*)&hl[r8 + m][c];
  const int jb = i0 + r8;
  const int jsw = (jb & ~127) | ((jb & 127) ^ ((c & 7) << 3));
  *(uint4*)(hT + ((size_t)b * F + c) * N + jsw) = *(uint4*)tb;
}

// ---------------- K2: per-batch unmasked max of f2 (upper bound for row max)
__global__ __launch_bounds__(256) void k2_f2max(const float* __restrict__ f2,
                                                float* __restrict__ f2max)
{
  __shared__ float s[256];
  const int b = blockIdx.x, tid = threadIdx.x;
  float m = -1e30f;
  for (int j = tid; j < N; j += 256) m = fmaxf(m, f2[b * N + j]);
  s[tid] = m;
  __syncthreads();
  for (int w = 128; w > 0; w >>= 1) {
    if (tid < w) s[tid] = fmaxf(s[tid], s[tid + w]);
    __syncthreads();
  }
  if (tid == 0) f2max[b] = s[0];
}

// ---------------- K3: fused mask + softmax + PV (bf16 MFMA) + elu
// T3/T4: raw s_barrier + COUNTED vmcnt(8) — adj/f2 prefetches stay in flight
// across the barrier; only the glds for the tile about to be consumed are
// drained. One barrier per j-tile. T5 setprio around MFMA.
__global__ __launch_bounds__(256) void k3_attn(
    const int* __restrict__ adj, const __hip_bfloat16* __restrict__ hT,
    const float* __restrict__ f1, const float* __restrict__ f2,
    const float* __restrict__ f2max, float* __restrict__ out)
{
  constexpr int RT = 32, JT = 128, NT = N / JT;  // 16 tiles
  __shared__ __hip_bfloat16 Pl[2][RT][JT];   // 16KB (XOR-swizzled)
  __shared__ __hip_bfloat16 Hl[2][F][JT];    // 32KB (linear; global pre-swizzled)
  __shared__ float rs[RT][8];                // 1KB
  __shared__ float rcp_s[RT];
  __shared__ float redt[2][32][32];          // 8KB

  const int tid = threadIdx.x;
  const int lane = tid & 63, wid = tid >> 6;
  const int ct = wid >> 1, kh = wid & 1;
  const int bi = blockIdx.x;
  const int b = bi / (N / RT);
  const int i0 = (bi % (N / RT)) * RT;

  const int r = tid >> 3, q = tid & 7;
  const float f1r = f1[b * N + i0 + r];
  const float Mr = lrelu(f1r + f2max[b]);    // >= true masked row max (lrelu monotone)

  const int* adjrow = adj + ((size_t)(b * N + i0 + r)) * N + 4 * q;
  const float* f2base = f2 + b * N + 4 * q;
  const int swp = (r & 7) << 3;

  const __hip_bfloat16* hsrc =
      hT + ((size_t)b * F + (wid * 16 + (lane >> 4))) * N + (lane & 15) * 8;

  float rowsum = 0.f;
  f32x16 acc;
  #pragma unroll
  for (int z = 0; z < 16; ++z) acc[z] = 0.f;

  const int arow = lane & 31;
  const int bcol = ct * 32 + (lane & 31);
  const int klo = kh * 64 + ((lane >> 5) * 8);

  #define STAGE_H(T, BUFI)                                                      \
    do {                                                                        \
      const __hip_bfloat16* s0_ = hsrc + (T) * JT;                              \
      char* lb_ = (char*)(&Hl[(BUFI)][0][0]) + wid * 4096;                      \
      _Pragma("unroll")                                                         \
      for (int q_ = 0; q_ < 4; ++q_) {                                          \
        __builtin_amdgcn_global_load_lds(                                       \
            (const __attribute__((address_space(1))) void*)(s0_ + q_ * 4 * N),  \
            (__attribute__((address_space(3))) void*)(lb_ + q_ * 1024),         \
            16, 0, 0);                                                          \
      }                                                                         \
    } while (0)

  #define LOADSET(AV, FV, T)                                                    \
    do {                                                                        \
      _Pragma("unroll")                                                         \
      for (int m_ = 0; m_ < 4; ++m_) {                                          \
        AV[m_] = *(const int4*)(adjrow + (T) * JT + 32 * m_);                   \
        FV[m_] = *(const float4*)(f2base + (T) * JT + 32 * m_);                 \
      }                                                                         \
    } while (0)

  // DO_STAGE: issue glds for tile T+1; DO_LOAD: issue adj/f2 regs for tile T+2.
  // VM: counted vmcnt at the barrier. Issue order glds -> adj pinned by
  // sched_barrier(0) so vmcnt(8) == "glds for next tile complete".
  #define ITER(T, AV, FV, BUF, VM, DO_STAGE, DO_LOAD)                           \
    do {                                                                        \
      _Pragma("unroll")                                                         \
      for (int m_ = 0; m_ < 4; ++m_) {                                          \
        const int* ai_ = (const int*)&AV[m_];                                   \
        const float* fe_ = (const float*)&FV[m_];                               \
        unsigned short pbm_[4] __attribute__((aligned(8)));                     \
        _Pragma("unroll")                                                       \
        for (int e_ = 0; e_ < 4; ++e_) {                                        \
          float s_ = lrelu(f1r + fe_[e_]);                                      \
          float p_ = (ai_[e_] > 0) ? __expf(s_ - Mr) : 0.f;                     \
          __hip_bfloat16 pbf_ = __float2bfloat16(p_);                           \
          rowsum += __bfloat162float(pbf_);                                     \
          pbm_[e_] = *(unsigned short*)&pbf_;                                   \
        }                                                                       \
        *(uint2*)&Pl[BUF][r][(4 * q + 32 * m_) ^ swp] = *(uint2*)pbm_;          \
      }                                                                         \
      asm volatile("s_waitcnt vmcnt(" #VM ") lgkmcnt(0)" ::: "memory");         \
      __builtin_amdgcn_s_barrier();                                             \
      __builtin_amdgcn_sched_barrier(0);                                        \
      if (DO_STAGE) STAGE_H((T) + 1, (BUF) ^ 1);                                \
      __builtin_amdgcn_sched_barrier(0);                                        \
      if (DO_LOAD) LOADSET(AV, FV, (T) + 2);                                    \
      __builtin_amdgcn_sched_barrier(0);                                        \
      __builtin_amdgcn_s_setprio(1);                                            \
      _Pragma("unroll")                                                         \
      for (int s_ = 0; s_ < 4; ++s_) {                                          \
        const int ak_ = klo + s_ * 16;                                          \
        bf16x8 af_ = *(const bf16x8*)&Pl[BUF][arow][ak_ ^ ((arow & 7) << 3)];   \
        bf16x8 bf_ = *(const bf16x8*)&Hl[BUF][bcol][ak_ ^ ((bcol & 7) << 3)];   \
        asm volatile("v_mfma_f32_32x32x16_bf16 %0, %1, %2, %0"                  \
                     : "+v"(acc) : "v"(af_), "v"(bf_));                         \
      }                                                                         \
      __builtin_amdgcn_s_setprio(0);                                            \
    } while (0)

  // prologue: glds(0) FIRST (so it is older than all adj loads), then tiles 0,1
  int4 a0v[4], a1v[4]; float4 g0v[4], g1v[4];
  STAGE_H(0, 0);
  __builtin_amdgcn_sched_barrier(0);
  LOADSET(a0v, g0v, 0);
  LOADSET(a1v, g1v, 1);

  for (int t = 0; t < NT - 2; t += 2) {
    ITER(t,     a0v, g0v, 0, 8, true, true);
    ITER(t + 1, a1v, g1v, 1, 8, true, true);
  }
  ITER(NT - 2, a0v, g0v, 0, 8, true,  false);  // stage Hl(15), no more adj
  ITER(NT - 1, a1v, g1v, 1, 0, false, false);  // final: full drain (4 glds only)
  #undef ITER
  #undef LOADSET
  #undef STAGE_H

  rs[r][q] = rowsum;
  if (kh == 1) {
    #pragma unroll
    for (int z = 0; z < 16; ++z)
      redt[ct][(z & 3) + 8 * (z >> 2) + 4 * (lane >> 5)][lane & 31] = acc[z];
  }
  __syncthreads();
  if (tid < 32) {
    float s = 0.f;
    #pragma unroll
    for (int m = 0; m < 8; ++m) s += rs[tid][m];
    rcp_s[tid] = 1.0f / fmaxf(s, 1e-30f);
  }
  __syncthreads();
  if (kh == 0) {
    #pragma unroll
    for (int z = 0; z < 16; ++z) {
      const int row = (z & 3) + 8 * (z >> 2) + 4 * (lane >> 5);
      float v = (acc[z] + redt[ct][row][lane & 31]) * rcp_s[row];
      v = v > 0.f ? v : expm1f(v);
      out[((size_t)(b * N + i0 + row)) * F + ct * 32 + (lane & 31)] = v;
    }
  }
}

extern "C" void kernel_launch(void* const* d_in, const int* in_sizes, int n_in,
                              void* d_out, int out_size, void* d_ws, size_t ws_size,
                              hipStream_t stream) {
  const float* inp = (const float*)d_in[0];
  const int*   adj = (const int*)d_in[1];
  const float* W   = (const float*)d_in[2];
  const float* a   = (const float*)d_in[3];
  float* out = (float*)d_out;

  char* ws = (char*)d_ws;
  __hip_bfloat16* hT = (__hip_bfloat16*)ws;
  float* f1  = (float*)(ws + (size_t)B * F * N * sizeof(__hip_bfloat16));
  float* f2  = f1 + (size_t)B * N;
  float* f2m = f2 + (size_t)B * N;

  hipLaunchKernelGGL(k1_project, dim3(B * N / 32), dim3(256), 0, stream, inp, W, a, hT, f1, f2);
  hipLaunchKernelGGL(k2_f2max, dim3(B), dim3(256), 0, stream, f2, f2m);
  hipLaunchKernelGGL(k3_attn, dim3(B * N / 32), dim3(256), 0, stream, adj, hT, f1, f2, f2m, out);
}